// Round 1
// baseline (604.080 us; speedup 1.0000x reference)
//
#include <hip/hip_runtime.h>

#define P_PTS 131072
#define CDIM  512
#define MCAP  1024
#define TLEN  262144
#define PORIG 163840

typedef unsigned short u16;
typedef __attribute__((ext_vector_type(8))) short short8;
typedef __attribute__((ext_vector_type(4))) float f32x4;

__device__ __forceinline__ float bf2f(u16 b) {
    return __uint_as_float(((unsigned)b) << 16);
}
__device__ __forceinline__ u16 f2bf(float f) {
    unsigned u = __float_as_uint(f);
    unsigned r = (u + 0x7FFFu + ((u >> 16) & 1u)) >> 16;
    return (u16)r;
}
__device__ __forceinline__ void ld16(const u16* g, u16* l) {
    __builtin_amdgcn_global_load_lds(
        (const __attribute__((address_space(1))) void*)g,
        (__attribute__((address_space(3))) void*)l, 16, 0, 0);
}

// ---- caption_embed f32 -> bf16 ----
__global__ __launch_bounds__(256) void cast_cap(const float* __restrict__ cap,
                                                u16* __restrict__ out) {
    int i = (blockIdx.x * 256 + threadIdx.x) * 4;
    float4 v = *(const float4*)(cap + i);
    u16* o = out + i;
    o[0] = f2bf(v.x); o[1] = f2bf(v.y); o[2] = f2bf(v.z); o[3] = f2bf(v.w);
}

// ---- gather voxel rows, L2-normalize, store bf16 [P][512]; 1 wave/row ----
__global__ __launch_bounds__(256) void gather_normalize(
    const float* __restrict__ adapter, const int* __restrict__ v2p,
    u16* __restrict__ feats) {
    int p = blockIdx.x * 4 + (threadIdx.x >> 6);
    int lane = threadIdx.x & 63;
    int vrow = v2p[p];
    const float4* src = (const float4*)(adapter + (size_t)vrow * CDIM);
    float4 x0 = src[lane * 2];
    float4 x1 = src[lane * 2 + 1];
    float ss = x0.x*x0.x + x0.y*x0.y + x0.z*x0.z + x0.w*x0.w
             + x1.x*x1.x + x1.y*x1.y + x1.z*x1.z + x1.w*x1.w;
    #pragma unroll
    for (int off = 32; off >= 1; off >>= 1) ss += __shfl_xor(ss, off, 64);
    float inv = 1.0f / fmaxf(sqrtf(ss), 1e-12f);
    u16 o[8];
    o[0]=f2bf(x0.x*inv); o[1]=f2bf(x0.y*inv); o[2]=f2bf(x0.z*inv); o[3]=f2bf(x0.w*inv);
    o[4]=f2bf(x1.x*inv); o[5]=f2bf(x1.y*inv); o[6]=f2bf(x1.z*inv); o[7]=f2bf(x1.w*inv);
    *(short8*)(feats + (size_t)p * CDIM + lane * 8) = *(short8*)o;
}

// ---- ptom scatter: last-write-wins == max index (values increasing) ----
__global__ __launch_bounds__(256) void scatter_ptom(const int* __restrict__ oidx,
                                                    int* __restrict__ ptom) {
    int i = blockIdx.x * 256 + threadIdx.x;
    atomicMax(&ptom[oidx[i]], i);
}

// ---- heavy GEMM: logits 128x128 tiles, epilogue exp-reduce -> atomicAdd lse_sum ----
__global__ __launch_bounds__(256) void lse_gemm(
    const u16* __restrict__ feats, const u16* __restrict__ capb,
    const float* __restrict__ lsc, float* __restrict__ lse_sum) {
    __shared__ __align__(16) u16 As[128 * 32];
    __shared__ __align__(16) u16 Bs[128 * 32];
    const int tid  = threadIdx.x;
    const int wave = tid >> 6;
    const int lane = tid & 63;
    const int col0 = blockIdx.x * 128;   // caption chunk (fast-varying for A-tile L2 reuse)
    const int row0 = blockIdx.y * 128;   // point chunk
    const int wm = (wave >> 1) * 64;
    const int wn = (wave & 1) * 64;
    const float sf = __expf(lsc[0]);

    f32x4 acc[4][4] = {};

    // staging: flat elem = tid*8 ; row = tid>>2, col = (tid&3)*8
    const int srow = tid >> 2;
    const int scol = (tid & 3) * 8;
    const u16* gA0 = feats + (size_t)(row0 + srow) * CDIM + scol;
    const u16* gB0 = capb  + (size_t)(col0 + srow) * CDIM + scol;
    u16* lA0 = As + wave * 512;   // wave-uniform base; HW scatters lane*16B
    u16* lB0 = Bs + wave * 512;

    const int mrow = lane & 15;
    const int quad = lane >> 4;
    const u16* rA = As + (wm + mrow) * 32 + quad * 8;
    const u16* rB = Bs + (wn + mrow) * 32 + quad * 8;

    for (int k0 = 0; k0 < CDIM; k0 += 32) {
        __syncthreads();
        ld16(gA0 + k0,              lA0);
        ld16(gA0 + 64 * CDIM + k0,  lA0 + 2048);
        ld16(gB0 + k0,              lB0);
        ld16(gB0 + 64 * CDIM + k0,  lB0 + 2048);
        __syncthreads();
        short8 af[4], bfr[4];
        #pragma unroll
        for (int i = 0; i < 4; ++i) af[i]  = *(const short8*)(rA + i * 512);
        #pragma unroll
        for (int j = 0; j < 4; ++j) bfr[j] = *(const short8*)(rB + j * 512);
        #pragma unroll
        for (int i = 0; i < 4; ++i)
            #pragma unroll
            for (int j = 0; j < 4; ++j)
                acc[i][j] = __builtin_amdgcn_mfma_f32_16x16x32_bf16(
                    af[i], bfr[j], acc[i][j], 0, 0, 0);
    }

    // epilogue: per-row sum of exp(logit - sf); C/D layout col=lane&15, row=quad*4+reg
    #pragma unroll
    for (int i = 0; i < 4; ++i) {
        float s[4] = {0.f, 0.f, 0.f, 0.f};
        #pragma unroll
        for (int j = 0; j < 4; ++j)
            #pragma unroll
            for (int r = 0; r < 4; ++r)
                s[r] += __expf(acc[i][j][r] * sf - sf);
        #pragma unroll
        for (int off = 8; off >= 1; off >>= 1)
            #pragma unroll
            for (int r = 0; r < 4; ++r)
                s[r] += __shfl_xor(s[r], off, 64);
        if (mrow == 0) {
            int rbase = row0 + wm + i * 16 + quad * 4;
            #pragma unroll
            for (int r = 0; r < 4; ++r)
                atomicAdd(&lse_sum[rbase + r], s[r]);
        }
    }
}

__device__ __forceinline__ int lower_bound(const int* __restrict__ a, int n, int key) {
    int lo = 0, hi = n;
    while (lo < hi) { int mid = (lo + hi) >> 1; if (a[mid] < key) lo = mid + 1; else hi = mid; }
    return lo;
}

// ---- per-segment: F[s] = sum feats rows (f32), L[s] = sum lse, counts ----
__global__ __launch_bounds__(256) void seg_reduce(
    const u16* __restrict__ feats, const float* __restrict__ lse_sum,
    const int* __restrict__ ptom, const int* __restrict__ ctpm,
    const int* __restrict__ seg, const float* __restrict__ lsc,
    float* __restrict__ F, float* __restrict__ Lout, float* __restrict__ realn) {
    int s = blockIdx.x;
    int tid = threadIdx.x, wave = tid >> 6, lane = tid & 63;
    int start = lower_bound(seg, TLEN, s);
    int end   = lower_bound(seg, TLEN, s + 1);
    float a[8] = {0,0,0,0,0,0,0,0};
    float Lacc = 0.f; int inv = 0;
    for (int r = start + wave; r < end; r += 4) {
        int m = ctpm[r];
        int g = ptom[m];
        int row = (g < 0) ? g + P_PTS : g;   // torch negative-index wrap
        if (lane == 0) { inv += (g < 0); Lacc += __logf(lse_sum[row]); }
        short8 v = *(const short8*)(feats + (size_t)row * CDIM + lane * 8);
        #pragma unroll
        for (int u = 0; u < 8; ++u) a[u] += bf2f((u16)v[u]);
    }
    __shared__ float pF[4][512];
    __shared__ float pL[4];
    __shared__ int   pI[4];
    #pragma unroll
    for (int u = 0; u < 8; ++u) pF[wave][lane * 8 + u] = a[u];
    if (lane == 0) { pL[wave] = Lacc; pI[wave] = inv; }
    __syncthreads();
    int c = tid * 2;
    float f0 = pF[0][c]   + pF[1][c]   + pF[2][c]   + pF[3][c];
    float f1 = pF[0][c+1] + pF[1][c+1] + pF[2][c+1] + pF[3][c+1];
    F[(size_t)s * CDIM + c]     = f0;
    F[(size_t)s * CDIM + c + 1] = f1;
    if (tid == 0) {
        float cnt  = (float)(end - start);
        float ninv = (float)(pI[0] + pI[1] + pI[2] + pI[3]);
        realn[s] = cnt - ninv;
        float sf = __expf(lsc[0]);
        Lout[s] = (pL[0] + pL[1] + pL[2] + pL[3]) + sf * cnt;   // each lse = sf + log(sum)
    }
}

// ---- pooled[s,m] = (sf * F[s].cap[m] - L[s]) * (1/real or 0) ; fp32 tiled ----
__global__ __launch_bounds__(256) void pooled_gemm(
    const float* __restrict__ F, const float* __restrict__ cap,
    const float* __restrict__ Lout, const float* __restrict__ realn,
    const float* __restrict__ lsc, float* __restrict__ out) {
    __shared__ float As[64][17], Bs[64][17];
    int tid = threadIdx.x;
    int tx = tid & 15, ty = tid >> 4;
    int m0 = blockIdx.x * 64, s0 = blockIdx.y * 64;
    float acc[4][4] = {};
    for (int k0 = 0; k0 < CDIM; k0 += 16) {
        #pragma unroll
        for (int u = 0; u < 4; ++u) {
            int idx = tid + u * 256;
            int r = idx >> 4, c = idx & 15;
            As[r][c] = F[(size_t)(s0 + r) * CDIM + k0 + c];
            Bs[r][c] = cap[(size_t)(m0 + r) * CDIM + k0 + c];
        }
        __syncthreads();
        #pragma unroll
        for (int kk = 0; kk < 16; ++kk) {
            float av[4], bv[4];
            #pragma unroll
            for (int u = 0; u < 4; ++u) { av[u] = As[ty*4+u][kk]; bv[u] = Bs[tx*4+u][kk]; }
            #pragma unroll
            for (int i = 0; i < 4; ++i)
                #pragma unroll
                for (int j = 0; j < 4; ++j) acc[i][j] += av[i] * bv[j];
        }
        __syncthreads();
    }
    float sf = __expf(lsc[0]);
    #pragma unroll
    for (int i = 0; i < 4; ++i) {
        int s = s0 + ty * 4 + i;
        float real = realn[s];
        float denom = real > 0.f ? 1.0f / real : 0.0f;
        float L = Lout[s];
        #pragma unroll
        for (int j = 0; j < 4; ++j) {
            int m = m0 + tx * 4 + j;
            out[(size_t)s * MCAP + m] = (sf * acc[i][j] - L) * denom;
        }
    }
}

__global__ __launch_bounds__(256) void write_tail(const float* __restrict__ realn,
                                                  float* __restrict__ out) {
    int s = blockIdx.x * 256 + threadIdx.x;
    if (s < MCAP) {
        float r = realn[s];
        out[MCAP * MCAP + s] = r;
        out[MCAP * MCAP + MCAP + s] = (r > 0.f) ? 1.0f : 0.0f;
    }
}

extern "C" void kernel_launch(void* const* d_in, const int* in_sizes, int n_in,
                              void* d_out, int out_size, void* d_ws, size_t ws_size,
                              hipStream_t stream) {
    const float* adapter = (const float*)d_in[0];
    const float* cap     = (const float*)d_in[1];
    const float* lsc     = (const float*)d_in[2];
    const int*   v2p     = (const int*)d_in[3];
    const int*   oidx    = (const int*)d_in[4];
    const int*   ctpm    = (const int*)d_in[5];
    const int*   seg     = (const int*)d_in[6];
    float* out = (float*)d_out;

    char* ws = (char*)d_ws;
    u16*   feats   = (u16*)(ws);                                  // 134217728 B
    u16*   capb    = (u16*)(ws + 134217728);                      //   1048576 B
    float* lse_sum = (float*)(ws + 135266304);                    //    524288 B
    int*   ptom    = (int*)(ws + 135790592);                      //    655360 B
    float* F       = (float*)(ws + 136445952);                    //   2097152 B
    float* Lout    = (float*)(ws + 138543104);                    //      4096 B
    float* realn   = (float*)(ws + 138547200);                    //      4096 B

    hipMemsetAsync(ptom, 0xFF, (size_t)PORIG * 4, stream);        // -1
    hipMemsetAsync(lse_sum, 0, (size_t)P_PTS * 4, stream);

    cast_cap<<<(MCAP * CDIM) / 1024, 256, 0, stream>>>(cap, capb);
    gather_normalize<<<P_PTS / 4, 256, 0, stream>>>(adapter, v2p, feats);
    scatter_ptom<<<P_PTS / 256, 256, 0, stream>>>(oidx, ptom);
    lse_gemm<<<dim3(MCAP / 128, P_PTS / 128), 256, 0, stream>>>(feats, capb, lsc, lse_sum);
    seg_reduce<<<MCAP, 256, 0, stream>>>(feats, lse_sum, ptom, ctpm, seg, lsc, F, Lout, realn);
    pooled_gemm<<<dim3(MCAP / 64, MCAP / 64), 256, 0, stream>>>(F, cap, Lout, realn, lsc, out);
    write_tail<<<4, 256, 0, stream>>>(realn, out);
}

// Round 2
// 442.890 us; speedup vs baseline: 1.3640x; 1.3640x over previous
//
#include <hip/hip_runtime.h>

#define P_PTS 131072
#define CDIM  512
#define MCAP  1024
#define TLEN  262144
#define PORIG 163840

typedef unsigned short u16;
typedef unsigned char  u8;
typedef __attribute__((ext_vector_type(8))) short short8;
typedef __attribute__((ext_vector_type(4))) float f32x4;
typedef __attribute__((ext_vector_type(8))) int int8v;
typedef __attribute__((ext_vector_type(4))) int int4v;

__device__ __forceinline__ u16 f2bf(float f) {
    unsigned u = __float_as_uint(f);
    unsigned r = (u + 0x7FFFu + ((u >> 16) & 1u)) >> 16;
    return (u16)r;
}
// OCP e4m3 decode: normals AND subnormals via f32-subnormal trick, 3 VALU ops
__device__ __forceinline__ float d_e4m3(unsigned x) {
    float f = __uint_as_float((x & 0x7Fu) << 20) * 0x1p120f;
    return __uint_as_float(__float_as_uint(f) | ((x & 0x80u) << 24));
}
__device__ __forceinline__ void ld16(const void* g, void* l) {
    __builtin_amdgcn_global_load_lds(
        (const __attribute__((address_space(1))) void*)g,
        (__attribute__((address_space(3))) void*)l, 16, 0, 0);
}

// ---- caption_embed f32 -> bf16 (for pooled mfma) + fp8 (for lse mfma) ----
__global__ __launch_bounds__(256) void cast_cap(const float* __restrict__ cap,
                                                u16* __restrict__ capb,
                                                u8* __restrict__ cap8) {
    int i = (blockIdx.x * 256 + threadIdx.x) * 4;
    float4 v = *(const float4*)(cap + i);
    u16* o = capb + i;
    o[0] = f2bf(v.x); o[1] = f2bf(v.y); o[2] = f2bf(v.z); o[3] = f2bf(v.w);
    int p = __builtin_amdgcn_cvt_pk_fp8_f32(v.x, v.y, 0, false);
    p = __builtin_amdgcn_cvt_pk_fp8_f32(v.z, v.w, p, true);
    *(int*)(cap8 + i) = p;
}

// ---- gather voxel rows, L2-normalize, store fp8 e4m3 [P][512]; 1 wave/row ----
__global__ __launch_bounds__(256) void gather_normalize(
    const float* __restrict__ adapter, const int* __restrict__ v2p,
    u8* __restrict__ feats8) {
    int p = blockIdx.x * 4 + (threadIdx.x >> 6);
    int lane = threadIdx.x & 63;
    int vrow = v2p[p];
    const float4* src = (const float4*)(adapter + (size_t)vrow * CDIM);
    float4 x0 = src[lane * 2];
    float4 x1 = src[lane * 2 + 1];
    float ss = x0.x*x0.x + x0.y*x0.y + x0.z*x0.z + x0.w*x0.w
             + x1.x*x1.x + x1.y*x1.y + x1.z*x1.z + x1.w*x1.w;
    #pragma unroll
    for (int off = 32; off >= 1; off >>= 1) ss += __shfl_xor(ss, off, 64);
    float inv = 1.0f / fmaxf(sqrtf(ss), 1e-12f);
    int lo = __builtin_amdgcn_cvt_pk_fp8_f32(x0.x*inv, x0.y*inv, 0, false);
    lo = __builtin_amdgcn_cvt_pk_fp8_f32(x0.z*inv, x0.w*inv, lo, true);
    int hi = __builtin_amdgcn_cvt_pk_fp8_f32(x1.x*inv, x1.y*inv, 0, false);
    hi = __builtin_amdgcn_cvt_pk_fp8_f32(x1.z*inv, x1.w*inv, hi, true);
    uint2 w; w.x = (unsigned)lo; w.y = (unsigned)hi;
    *(uint2*)(feats8 + (size_t)p * CDIM + lane * 8) = w;
}

// ---- ptom scatter: last-write-wins == max index (values increasing) ----
__global__ __launch_bounds__(256) void scatter_ptom(const int* __restrict__ oidx,
                                                    int* __restrict__ ptom) {
    int i = blockIdx.x * 256 + threadIdx.x;
    atomicMax(&ptom[oidx[i]], i);
}

// ---- heavy GEMM: MX-fp8 K=128 MFMA, 128x128 tiles, XOR-swizzled LDS,
//      XCD-aware grid swizzle; epilogue exp-reduce -> atomicAdd lse_sum ----
__global__ __launch_bounds__(256) void lse_gemm(
    const u8* __restrict__ feats8, const u8* __restrict__ cap8,
    const float* __restrict__ lsc, float* __restrict__ lse_sum) {
    __shared__ __align__(16) u8 As[16384];
    __shared__ __align__(16) u8 Bs[16384];
    const int tid  = threadIdx.x;
    const int wave = tid >> 6;
    const int lane = tid & 63;
    // swizzle: all 8 col-tiles of one row-tile share id%8 (same XCD under RR)
    const unsigned id = blockIdx.x;
    const int col0 = (int)((id >> 3) & 7u) * 128;
    const int row0 = (int)((id & 7u) + 8u * (id >> 6)) * 128;
    const int wm = (wave >> 1) * 64;
    const int wn = (wave & 1) * 64;
    const float sf = __expf(lsc[0]);

    f32x4 acc[4][4] = {};

    // staging: per call c, thread stages 16B phys-chunk p=c*256+tid
    // phys layout: chunk p <-> (row=p>>3, physc=p&7), logical kchunk = physc ^ (row&7)
    const int srow = tid >> 3;                      // 0..31
    const int kc   = (tid & 7) ^ (srow & 7);
    const u8* gA = feats8 + (size_t)(row0 + srow) * CDIM + kc * 16;
    const u8* gB = cap8   + (size_t)(col0 + srow) * CDIM + kc * 16;
    u8* lA = As + wave * 1024;
    u8* lB = Bs + wave * 1024;

    const int m = lane & 15;
    const int q = lane >> 4;
    const u8* rA1 = As + (size_t)((wm + m) * 8 + ((2*q)   ^ (m & 7))) * 16;
    const u8* rA2 = As + (size_t)((wm + m) * 8 + ((2*q+1) ^ (m & 7))) * 16;
    const u8* rB1 = Bs + (size_t)((wn + m) * 8 + ((2*q)   ^ (m & 7))) * 16;
    const u8* rB2 = Bs + (size_t)((wn + m) * 8 + ((2*q+1) ^ (m & 7))) * 16;

    for (int k0 = 0; k0 < CDIM; k0 += 128) {
        __syncthreads();
        #pragma unroll
        for (int c = 0; c < 4; ++c) {
            ld16(gA + (size_t)c * 32 * CDIM + k0, lA + c * 4096);
            ld16(gB + (size_t)c * 32 * CDIM + k0, lB + c * 4096);
        }
        __syncthreads();
        int8v af[4], bv[4];
        #pragma unroll
        for (int i = 0; i < 4; ++i) {
            int4v lo = *(const int4v*)(rA1 + i * 2048);
            int4v hi = *(const int4v*)(rA2 + i * 2048);
            af[i][0]=lo[0]; af[i][1]=lo[1]; af[i][2]=lo[2]; af[i][3]=lo[3];
            af[i][4]=hi[0]; af[i][5]=hi[1]; af[i][6]=hi[2]; af[i][7]=hi[3];
        }
        #pragma unroll
        for (int j = 0; j < 4; ++j) {
            int4v lo = *(const int4v*)(rB1 + j * 2048);
            int4v hi = *(const int4v*)(rB2 + j * 2048);
            bv[j][0]=lo[0]; bv[j][1]=lo[1]; bv[j][2]=lo[2]; bv[j][3]=lo[3];
            bv[j][4]=hi[0]; bv[j][5]=hi[1]; bv[j][6]=hi[2]; bv[j][7]=hi[3];
        }
        #pragma unroll
        for (int i = 0; i < 4; ++i)
            #pragma unroll
            for (int j = 0; j < 4; ++j)
                acc[i][j] = __builtin_amdgcn_mfma_scale_f32_16x16x128_f8f6f4(
                    af[i], bv[j], acc[i][j], 0, 0, /*opsel_a*/0, /*scale_a*/127,
                    /*opsel_b*/0, /*scale_b*/127);   // e8m0 127 = x1.0
    }

    // epilogue: per-row sum of exp(logit - sf); C/D: col=lane&15, row=q*4+r
    #pragma unroll
    for (int i = 0; i < 4; ++i) {
        float s4[4] = {0.f, 0.f, 0.f, 0.f};
        #pragma unroll
        for (int j = 0; j < 4; ++j)
            #pragma unroll
            for (int r = 0; r < 4; ++r)
                s4[r] += __expf(acc[i][j][r] * sf - sf);
        #pragma unroll
        for (int off = 8; off >= 1; off >>= 1)
            #pragma unroll
            for (int r = 0; r < 4; ++r)
                s4[r] += __shfl_xor(s4[r], off, 64);
        if (m == 0) {
            int rbase = row0 + wm + i * 16 + q * 4;
            #pragma unroll
            for (int r = 0; r < 4; ++r)
                atomicAdd(&lse_sum[rbase + r], s4[r]);
        }
    }
}

__device__ __forceinline__ int lower_bound(const int* __restrict__ a, int n, int key) {
    int lo = 0, hi = n;
    while (lo < hi) { int mid = (lo + hi) >> 1; if (a[mid] < key) lo = mid + 1; else hi = mid; }
    return lo;
}

// ---- per-segment: Fb[s] = sum feats rows (bf16 out), L[s] = sum lse, counts ----
__global__ __launch_bounds__(1024) void seg_reduce(
    const u8* __restrict__ feats8, const float* __restrict__ lse_sum,
    const int* __restrict__ ptom, const int* __restrict__ ctpm,
    const int* __restrict__ seg, const float* __restrict__ lsc,
    u16* __restrict__ Fb, float* __restrict__ Lout, float* __restrict__ realn) {
    int s = blockIdx.x;
    int tid = threadIdx.x, wave = tid >> 6, lane = tid & 63;
    int start = lower_bound(seg, TLEN, s);
    int end   = lower_bound(seg, TLEN, s + 1);
    float a[8] = {0,0,0,0,0,0,0,0};
    float Lacc = 0.f; int inv = 0;
    for (int r = start + wave; r < end; r += 16) {
        int g = ptom[ctpm[r]];
        int row = (g < 0) ? g + P_PTS : g;   // torch negative-index wrap
        if (lane == 0) { inv += (g < 0); Lacc += __logf(lse_sum[row]); }
        uint2 v = *(const uint2*)(feats8 + (size_t)row * CDIM + lane * 8);
        a[0] += d_e4m3(v.x);       a[1] += d_e4m3(v.x >> 8);
        a[2] += d_e4m3(v.x >> 16); a[3] += d_e4m3(v.x >> 24);
        a[4] += d_e4m3(v.y);       a[5] += d_e4m3(v.y >> 8);
        a[6] += d_e4m3(v.y >> 16); a[7] += d_e4m3(v.y >> 24);
    }
    __shared__ float pF[16][512];
    __shared__ float pL[16];
    __shared__ int   pI[16];
    #pragma unroll
    for (int u = 0; u < 8; ++u) pF[wave][lane * 8 + u] = a[u];
    if (lane == 0) { pL[wave] = Lacc; pI[wave] = inv; }
    __syncthreads();
    if (tid < 512) {
        float f = 0.f;
        #pragma unroll
        for (int w = 0; w < 16; ++w) f += pF[w][tid];
        Fb[(size_t)s * CDIM + tid] = f2bf(f);
    }
    if (tid == 0) {
        float cnt = (float)(end - start);
        float Ls = 0.f; int ninv = 0;
        #pragma unroll
        for (int w = 0; w < 16; ++w) { Ls += pL[w]; ninv += pI[w]; }
        realn[s] = cnt - (float)ninv;
        Lout[s] = Ls + __expf(lsc[0]) * cnt;   // each lse = sf + log(sum)
    }
}

// ---- pooled[s,m] = (sf * Fb[s].capb[m] - L[s]) * (1/real or 0); bf16 MFMA ----
__global__ __launch_bounds__(256) void pooled_gemm(
    const u16* __restrict__ Fb, const u16* __restrict__ capb,
    const float* __restrict__ Lout, const float* __restrict__ realn,
    const float* __restrict__ lsc, float* __restrict__ out) {
    __shared__ __align__(16) u16 As[128 * 32];
    __shared__ __align__(16) u16 Bs[128 * 32];
    const int tid  = threadIdx.x;
    const int wave = tid >> 6;
    const int lane = tid & 63;
    const int col0 = blockIdx.x * 128;   // captions
    const int row0 = blockIdx.y * 128;   // segments
    const int wm = (wave >> 1) * 64;
    const int wn = (wave & 1) * 64;
    const float sf = __expf(lsc[0]);
    f32x4 acc[4][4] = {};
    const int srow = tid >> 2;
    const int scol = (tid & 3) * 8;
    const u16* gA0 = Fb   + (size_t)(row0 + srow) * CDIM + scol;
    const u16* gB0 = capb + (size_t)(col0 + srow) * CDIM + scol;
    u16* lA0 = As + wave * 512;
    u16* lB0 = Bs + wave * 512;
    const int mrow = lane & 15;
    const int quad = lane >> 4;
    const u16* rA = As + (wm + mrow) * 32 + quad * 8;
    const u16* rB = Bs + (wn + mrow) * 32 + quad * 8;
    for (int k0 = 0; k0 < CDIM; k0 += 32) {
        __syncthreads();
        ld16(gA0 + k0,             lA0);
        ld16(gA0 + 64 * CDIM + k0, lA0 + 2048);
        ld16(gB0 + k0,             lB0);
        ld16(gB0 + 64 * CDIM + k0, lB0 + 2048);
        __syncthreads();
        short8 af[4], bfr[4];
        #pragma unroll
        for (int i = 0; i < 4; ++i) af[i]  = *(const short8*)(rA + i * 512);
        #pragma unroll
        for (int j = 0; j < 4; ++j) bfr[j] = *(const short8*)(rB + j * 512);
        #pragma unroll
        for (int i = 0; i < 4; ++i)
            #pragma unroll
            for (int j = 0; j < 4; ++j)
                acc[i][j] = __builtin_amdgcn_mfma_f32_16x16x32_bf16(
                    af[i], bfr[j], acc[i][j], 0, 0, 0);
    }
    #pragma unroll
    for (int i = 0; i < 4; ++i) {
        #pragma unroll
        for (int r = 0; r < 4; ++r) {
            int s = row0 + wm + i * 16 + quad * 4 + r;
            float rn = realn[s];
            float dn = rn > 0.f ? 1.0f / rn : 0.0f;
            float L = Lout[s];
            #pragma unroll
            for (int j = 0; j < 4; ++j) {
                int mc = col0 + wn + j * 16 + mrow;
                out[(size_t)s * MCAP + mc] = (sf * acc[i][j][r] - L) * dn;
            }
        }
    }
}

__global__ __launch_bounds__(256) void write_tail(const float* __restrict__ realn,
                                                  float* __restrict__ out) {
    int s = blockIdx.x * 256 + threadIdx.x;
    if (s < MCAP) {
        float r = realn[s];
        out[MCAP * MCAP + s] = r;
        out[MCAP * MCAP + MCAP + s] = (r > 0.f) ? 1.0f : 0.0f;
    }
}

extern "C" void kernel_launch(void* const* d_in, const int* in_sizes, int n_in,
                              void* d_out, int out_size, void* d_ws, size_t ws_size,
                              hipStream_t stream) {
    const float* adapter = (const float*)d_in[0];
    const float* cap     = (const float*)d_in[1];
    const float* lsc     = (const float*)d_in[2];
    const int*   v2p     = (const int*)d_in[3];
    const int*   oidx    = (const int*)d_in[4];
    const int*   ctpm    = (const int*)d_in[5];
    const int*   seg     = (const int*)d_in[6];
    float* out = (float*)d_out;

    char* ws = (char*)d_ws;
    u8*    feats8  = (u8*)(ws);                                   // 67,108,864 B
    u8*    cap8    = (u8*)(ws + 67108864);                        //    524,288 B
    u16*   capb    = (u16*)(ws + 67633152);                       //  1,048,576 B
    float* lse_sum = (float*)(ws + 68681728);                     //    524,288 B
    int*   ptom    = (int*)(ws + 69206016);                       //    655,360 B
    u16*   Fb      = (u16*)(ws + 69861376);                       //  1,048,576 B
    float* Lout    = (float*)(ws + 70909952);                     //      4,096 B
    float* realn   = (float*)(ws + 70914048);                     //      4,096 B

    hipMemsetAsync(ptom, 0xFF, (size_t)PORIG * 4, stream);        // -1
    hipMemsetAsync(lse_sum, 0, (size_t)P_PTS * 4, stream);

    cast_cap<<<(MCAP * CDIM) / 1024, 256, 0, stream>>>(cap, capb, cap8);
    gather_normalize<<<P_PTS / 4, 256, 0, stream>>>(adapter, v2p, feats8);
    scatter_ptom<<<P_PTS / 256, 256, 0, stream>>>(oidx, ptom);
    lse_gemm<<<(P_PTS / 128) * (MCAP / 128), 256, 0, stream>>>(feats8, cap8, lsc, lse_sum);
    seg_reduce<<<MCAP, 1024, 0, stream>>>(feats8, lse_sum, ptom, ctpm, seg, lsc, Fb, Lout, realn);
    pooled_gemm<<<dim3(MCAP / 128, MCAP / 128), 256, 0, stream>>>(Fb, capb, Lout, realn, lsc, out);
    write_tail<<<4, 256, 0, stream>>>(realn, out);
}

// Round 3
// 410.243 us; speedup vs baseline: 1.4725x; 1.0796x over previous
//
#include <hip/hip_runtime.h>

#define P_PTS 131072
#define CDIM  512
#define MCAP  1024
#define TLEN  262144
#define PORIG 163840

typedef unsigned short u16;
typedef unsigned char  u8;
typedef __attribute__((ext_vector_type(8))) short short8;
typedef __attribute__((ext_vector_type(4))) float f32x4;
typedef __attribute__((ext_vector_type(8))) int int8v;
typedef __attribute__((ext_vector_type(4))) int int4v;

__device__ __forceinline__ u16 f2bf(float f) {
    unsigned u = __float_as_uint(f);
    unsigned r = (u + 0x7FFFu + ((u >> 16) & 1u)) >> 16;
    return (u16)r;
}
// OCP e4m3 decode: normals AND subnormals via f32-subnormal trick
__device__ __forceinline__ float d_e4m3(unsigned x) {
    float f = __uint_as_float((x & 0x7Fu) << 20) * 0x1p120f;
    return __uint_as_float(__float_as_uint(f) | ((x & 0x80u) << 24));
}
__device__ __forceinline__ void ld16(const void* g, void* l) {
    __builtin_amdgcn_global_load_lds(
        (const __attribute__((address_space(1))) void*)g,
        (__attribute__((address_space(3))) void*)l, 16, 0, 0);
}

// ---- prep: cast caption_embed (bf16 + fp8), scatter ptom, zero lse_sum ----
__global__ __launch_bounds__(256) void prep(const float* __restrict__ cap,
                                            const int* __restrict__ oidx,
                                            u16* __restrict__ capb,
                                            u8* __restrict__ cap8,
                                            int* __restrict__ ptom,
                                            float* __restrict__ lse_sum) {
    int b = blockIdx.x, tid = threadIdx.x;
    if (b < 512) {
        int i = (b * 256 + tid) * 4;
        float4 v = *(const float4*)(cap + i);
        u16* o = capb + i;
        o[0] = f2bf(v.x); o[1] = f2bf(v.y); o[2] = f2bf(v.z); o[3] = f2bf(v.w);
        int p = __builtin_amdgcn_cvt_pk_fp8_f32(v.x, v.y, 0, false);
        p = __builtin_amdgcn_cvt_pk_fp8_f32(v.z, v.w, p, true);
        *(int*)(cap8 + i) = p;
        int t = b * 256 + tid;                 // [0, 131072)
        atomicMax(&ptom[oidx[t]], t);          // last-write-wins == max (values increasing)
    } else {
        int j = (b - 512) * 256 + tid;         // [0, 131072)
        lse_sum[j] = 0.0f;
    }
}

// ---- gather voxel rows, L2-normalize, store fp8 e4m3 [P][512]; 1 wave/row ----
__global__ __launch_bounds__(256) void gather_normalize(
    const float* __restrict__ adapter, const int* __restrict__ v2p,
    u8* __restrict__ feats8) {
    int p = blockIdx.x * 4 + (threadIdx.x >> 6);
    int lane = threadIdx.x & 63;
    int vrow = v2p[p];
    const float4* src = (const float4*)(adapter + (size_t)vrow * CDIM);
    float4 x0 = src[lane * 2];
    float4 x1 = src[lane * 2 + 1];
    float ss = x0.x*x0.x + x0.y*x0.y + x0.z*x0.z + x0.w*x0.w
             + x1.x*x1.x + x1.y*x1.y + x1.z*x1.z + x1.w*x1.w;
    #pragma unroll
    for (int off = 32; off >= 1; off >>= 1) ss += __shfl_xor(ss, off, 64);
    float inv = 1.0f / fmaxf(sqrtf(ss), 1e-12f);
    int lo = __builtin_amdgcn_cvt_pk_fp8_f32(x0.x*inv, x0.y*inv, 0, false);
    lo = __builtin_amdgcn_cvt_pk_fp8_f32(x0.z*inv, x0.w*inv, lo, true);
    int hi = __builtin_amdgcn_cvt_pk_fp8_f32(x1.x*inv, x1.y*inv, 0, false);
    hi = __builtin_amdgcn_cvt_pk_fp8_f32(x1.z*inv, x1.w*inv, hi, true);
    uint2 w; w.x = (unsigned)lo; w.y = (unsigned)hi;
    *(uint2*)(feats8 + (size_t)p * CDIM + lane * 8) = w;
}

// ---- flatten the 2-level chase: rows[t] = row | (invalid << 31) ----
__global__ __launch_bounds__(256) void make_rows(const int* __restrict__ ctpm,
                                                 const int* __restrict__ ptom,
                                                 unsigned* __restrict__ rows) {
    int t = blockIdx.x * 256 + threadIdx.x;
    int g = ptom[ctpm[t]];
    rows[t] = (g < 0) ? ((unsigned)(g + P_PTS) | 0x80000000u) : (unsigned)g;
}

// ---- heavy GEMM: MX-fp8 K=128 MFMA, 128x128 tiles, XOR-swizzled LDS,
//      XCD-aware grid swizzle; epilogue exp-reduce -> atomicAdd lse_sum ----
__global__ __launch_bounds__(256) void lse_gemm(
    const u8* __restrict__ feats8, const u8* __restrict__ cap8,
    const float* __restrict__ lsc, float* __restrict__ lse_sum) {
    __shared__ __align__(16) u8 As[16384];
    __shared__ __align__(16) u8 Bs[16384];
    const int tid  = threadIdx.x;
    const int wave = tid >> 6;
    const int lane = tid & 63;
    const unsigned id = blockIdx.x;
    const int col0 = (int)((id >> 3) & 7u) * 128;
    const int row0 = (int)((id & 7u) + 8u * (id >> 6)) * 128;
    const int wm = (wave >> 1) * 64;
    const int wn = (wave & 1) * 64;
    const float sf = __expf(lsc[0]);

    f32x4 acc[4][4] = {};

    const int srow = tid >> 3;                      // 0..31
    const int kc   = (tid & 7) ^ (srow & 7);
    const u8* gA = feats8 + (size_t)(row0 + srow) * CDIM + kc * 16;
    const u8* gB = cap8   + (size_t)(col0 + srow) * CDIM + kc * 16;
    u8* lA = As + wave * 1024;
    u8* lB = Bs + wave * 1024;

    const int m = lane & 15;
    const int q = lane >> 4;
    const u8* rA1 = As + (size_t)((wm + m) * 8 + ((2*q)   ^ (m & 7))) * 16;
    const u8* rA2 = As + (size_t)((wm + m) * 8 + ((2*q+1) ^ (m & 7))) * 16;
    const u8* rB1 = Bs + (size_t)((wn + m) * 8 + ((2*q)   ^ (m & 7))) * 16;
    const u8* rB2 = Bs + (size_t)((wn + m) * 8 + ((2*q+1) ^ (m & 7))) * 16;

    #pragma unroll
    for (int k0 = 0; k0 < CDIM; k0 += 128) {
        __syncthreads();
        #pragma unroll
        for (int c = 0; c < 4; ++c) {
            ld16(gA + (size_t)c * 32 * CDIM + k0, lA + c * 4096);
            ld16(gB + (size_t)c * 32 * CDIM + k0, lB + c * 4096);
        }
        __syncthreads();
        int8v af[4], bv[4];
        #pragma unroll
        for (int i = 0; i < 4; ++i) {
            int4v lo = *(const int4v*)(rA1 + i * 2048);
            int4v hi = *(const int4v*)(rA2 + i * 2048);
            af[i][0]=lo[0]; af[i][1]=lo[1]; af[i][2]=lo[2]; af[i][3]=lo[3];
            af[i][4]=hi[0]; af[i][5]=hi[1]; af[i][6]=hi[2]; af[i][7]=hi[3];
        }
        #pragma unroll
        for (int j = 0; j < 4; ++j) {
            int4v lo = *(const int4v*)(rB1 + j * 2048);
            int4v hi = *(const int4v*)(rB2 + j * 2048);
            bv[j][0]=lo[0]; bv[j][1]=lo[1]; bv[j][2]=lo[2]; bv[j][3]=lo[3];
            bv[j][4]=hi[0]; bv[j][5]=hi[1]; bv[j][6]=hi[2]; bv[j][7]=hi[3];
        }
        #pragma unroll
        for (int i = 0; i < 4; ++i)
            #pragma unroll
            for (int j = 0; j < 4; ++j)
                acc[i][j] = __builtin_amdgcn_mfma_scale_f32_16x16x128_f8f6f4(
                    af[i], bv[j], acc[i][j], 0, 0, 0, 127, 0, 127); // e8m0 127 = x1.0
    }

    #pragma unroll
    for (int i = 0; i < 4; ++i) {
        float s4[4] = {0.f, 0.f, 0.f, 0.f};
        #pragma unroll
        for (int j = 0; j < 4; ++j)
            #pragma unroll
            for (int r = 0; r < 4; ++r)
                s4[r] += __expf(acc[i][j][r] * sf - sf);
        #pragma unroll
        for (int off = 8; off >= 1; off >>= 1)
            #pragma unroll
            for (int r = 0; r < 4; ++r)
                s4[r] += __shfl_xor(s4[r], off, 64);
        if (m == 0) {
            int rbase = row0 + wm + i * 16 + q * 4;
            #pragma unroll
            for (int r = 0; r < 4; ++r)
                atomicAdd(&lse_sum[rbase + r], s4[r]);
        }
    }
}

__device__ __forceinline__ int lower_bound(const int* __restrict__ a, int n, int key) {
    int lo = 0, hi = n;
    while (lo < hi) { int mid = (lo + hi) >> 1; if (a[mid] < key) lo = mid + 1; else hi = mid; }
    return lo;
}

// ---- per-segment: Fb[s] = sum feats rows (bf16), L[s] = sum log lse_sum, counts ----
__global__ __launch_bounds__(1024) void seg_reduce(
    const u8* __restrict__ feats8, const float* __restrict__ lse_sum,
    const unsigned* __restrict__ rows, const int* __restrict__ seg,
    const float* __restrict__ lsc,
    u16* __restrict__ Fb, float* __restrict__ Lout, float* __restrict__ realn) {
    int s = blockIdx.x;
    int tid = threadIdx.x, wave = tid >> 6, lane = tid & 63;
    int start = lower_bound(seg, TLEN, s);
    int end   = lower_bound(seg, TLEN, s + 1);
    float a[8] = {0,0,0,0,0,0,0,0};
    float Lacc = 0.f; int inv = 0;
    int r = start + wave;
    // dual-issue: two independent rows per iteration to hide L3 latency
    for (; r + 16 < end; r += 32) {
        unsigned p0 = rows[r], p1 = rows[r + 16];
        int r0 = (int)(p0 & 0x7FFFFFFFu), r1 = (int)(p1 & 0x7FFFFFFFu);
        uint2 v0 = *(const uint2*)(feats8 + (size_t)r0 * CDIM + lane * 8);
        uint2 v1 = *(const uint2*)(feats8 + (size_t)r1 * CDIM + lane * 8);
        if (lane == 0) {
            inv += (int)(p0 >> 31) + (int)(p1 >> 31);
            Lacc += __logf(lse_sum[r0]) + __logf(lse_sum[r1]);
        }
        a[0] += d_e4m3(v0.x);       a[1] += d_e4m3(v0.x >> 8);
        a[2] += d_e4m3(v0.x >> 16); a[3] += d_e4m3(v0.x >> 24);
        a[4] += d_e4m3(v0.y);       a[5] += d_e4m3(v0.y >> 8);
        a[6] += d_e4m3(v0.y >> 16); a[7] += d_e4m3(v0.y >> 24);
        a[0] += d_e4m3(v1.x);       a[1] += d_e4m3(v1.x >> 8);
        a[2] += d_e4m3(v1.x >> 16); a[3] += d_e4m3(v1.x >> 24);
        a[4] += d_e4m3(v1.y);       a[5] += d_e4m3(v1.y >> 8);
        a[6] += d_e4m3(v1.y >> 16); a[7] += d_e4m3(v1.y >> 24);
    }
    if (r < end) {
        unsigned p0 = rows[r];
        int r0 = (int)(p0 & 0x7FFFFFFFu);
        uint2 v0 = *(const uint2*)(feats8 + (size_t)r0 * CDIM + lane * 8);
        if (lane == 0) { inv += (int)(p0 >> 31); Lacc += __logf(lse_sum[r0]); }
        a[0] += d_e4m3(v0.x);       a[1] += d_e4m3(v0.x >> 8);
        a[2] += d_e4m3(v0.x >> 16); a[3] += d_e4m3(v0.x >> 24);
        a[4] += d_e4m3(v0.y);       a[5] += d_e4m3(v0.y >> 8);
        a[6] += d_e4m3(v0.y >> 16); a[7] += d_e4m3(v0.y >> 24);
    }
    __shared__ float pF[16][512];
    __shared__ float pL[16];
    __shared__ int   pI[16];
    #pragma unroll
    for (int u = 0; u < 8; ++u) pF[wave][lane * 8 + u] = a[u];
    if (lane == 0) { pL[wave] = Lacc; pI[wave] = inv; }
    __syncthreads();
    if (tid < 512) {
        float f = 0.f;
        #pragma unroll
        for (int w = 0; w < 16; ++w) f += pF[w][tid];
        Fb[(size_t)s * CDIM + tid] = f2bf(f);
    }
    if (tid == 0) {
        float cnt = (float)(end - start);
        float Ls = 0.f; int ninv = 0;
        #pragma unroll
        for (int w = 0; w < 16; ++w) { Ls += pL[w]; ninv += pI[w]; }
        realn[s] = cnt - (float)ninv;
        Lout[s] = Ls + __expf(lsc[0]) * cnt;   // each lse = sf + log(sum)
    }
}

// ---- pooled[s,m] = (sf*Fb[s].capb[m] - L[s]) * (1/real or 0); 64x64 bf16 MFMA,
//      256 blocks; col-0 blocks also write the tail outputs ----
__global__ __launch_bounds__(256) void pooled_gemm(
    const u16* __restrict__ Fb, const u16* __restrict__ capb,
    const float* __restrict__ Lout, const float* __restrict__ realn,
    const float* __restrict__ lsc, float* __restrict__ out) {
    __shared__ __align__(16) u16 As[64 * 32];
    __shared__ __align__(16) u16 Bs[64 * 32];
    const int tid  = threadIdx.x;
    const int wave = tid >> 6;
    const int lane = tid & 63;
    const int col0 = blockIdx.x * 64;   // captions
    const int row0 = blockIdx.y * 64;   // segments
    const int wm = (wave >> 1) * 32;
    const int wn = (wave & 1) * 32;
    const float sf = __expf(lsc[0]);
    f32x4 acc[2][2] = {};
    const int srow = tid >> 2;          // 0..63
    const int scol = (tid & 3) * 8;
    const u16* gA0 = Fb   + (size_t)(row0 + srow) * CDIM + scol;
    const u16* gB0 = capb + (size_t)(col0 + srow) * CDIM + scol;
    u16* lA0 = As + wave * 512;
    u16* lB0 = Bs + wave * 512;
    const int mrow = lane & 15;
    const int quad = lane >> 4;
    const u16* rA = As + (wm + mrow) * 32 + quad * 8;
    const u16* rB = Bs + (wn + mrow) * 32 + quad * 8;
    #pragma unroll 4
    for (int k0 = 0; k0 < CDIM; k0 += 32) {
        __syncthreads();
        ld16(gA0 + k0, lA0);
        ld16(gB0 + k0, lB0);
        __syncthreads();
        short8 af[2], bfr[2];
        #pragma unroll
        for (int i = 0; i < 2; ++i) af[i]  = *(const short8*)(rA + i * 512);
        #pragma unroll
        for (int j = 0; j < 2; ++j) bfr[j] = *(const short8*)(rB + j * 512);
        #pragma unroll
        for (int i = 0; i < 2; ++i)
            #pragma unroll
            for (int j = 0; j < 2; ++j)
                acc[i][j] = __builtin_amdgcn_mfma_f32_16x16x32_bf16(
                    af[i], bfr[j], acc[i][j], 0, 0, 0);
    }
    #pragma unroll
    for (int i = 0; i < 2; ++i) {
        #pragma unroll
        for (int r = 0; r < 4; ++r) {
            int s = row0 + wm + i * 16 + quad * 4 + r;
            float rn = realn[s];
            float dn = rn > 0.f ? 1.0f / rn : 0.0f;
            float L = Lout[s];
            #pragma unroll
            for (int j = 0; j < 2; ++j) {
                int mc = col0 + wn + j * 16 + mrow;
                out[(size_t)s * MCAP + mc] = (sf * acc[i][j][r] - L) * dn;
            }
        }
    }
    if (col0 == 0 && tid < 64) {
        int s = row0 + tid;
        float rv = realn[s];
        out[MCAP * MCAP + s] = rv;
        out[MCAP * MCAP + MCAP + s] = (rv > 0.f) ? 1.0f : 0.0f;
    }
}

extern "C" void kernel_launch(void* const* d_in, const int* in_sizes, int n_in,
                              void* d_out, int out_size, void* d_ws, size_t ws_size,
                              hipStream_t stream) {
    const float* adapter = (const float*)d_in[0];
    const float* cap     = (const float*)d_in[1];
    const float* lsc     = (const float*)d_in[2];
    const int*   v2p     = (const int*)d_in[3];
    const int*   oidx    = (const int*)d_in[4];
    const int*   ctpm    = (const int*)d_in[5];
    const int*   seg     = (const int*)d_in[6];
    float* out = (float*)d_out;

    char* ws = (char*)d_ws;
    u8*       feats8  = (u8*)(ws);                                // 67,108,864 B
    u8*       cap8    = (u8*)(ws + 67108864);                     //    524,288 B
    u16*      capb    = (u16*)(ws + 67633152);                    //  1,048,576 B
    float*    lse_sum = (float*)(ws + 68681728);                  //    524,288 B
    int*      ptom    = (int*)(ws + 69206016);                    //    655,360 B
    unsigned* rows    = (unsigned*)(ws + 69861376);               //  1,048,576 B
    u16*      Fb      = (u16*)(ws + 70909952);                    //  1,048,576 B
    float*    Lout    = (float*)(ws + 71958528);                  //      4,096 B
    float*    realn   = (float*)(ws + 71962624);                  //      4,096 B

    hipMemsetAsync(ptom, 0xFF, (size_t)PORIG * 4, stream);        // -1

    prep<<<1024, 256, 0, stream>>>(cap, oidx, capb, cap8, ptom, lse_sum);
    gather_normalize<<<P_PTS / 4, 256, 0, stream>>>(adapter, v2p, feats8);
    make_rows<<<TLEN / 256, 256, 0, stream>>>(ctpm, ptom, rows);
    lse_gemm<<<(P_PTS / 128) * (MCAP / 128), 256, 0, stream>>>(feats8, cap8, lsc, lse_sum);
    seg_reduce<<<MCAP, 1024, 0, stream>>>(feats8, lse_sum, rows, seg, lsc, Fb, Lout, realn);
    pooled_gemm<<<dim3(MCAP / 64, MCAP / 64), 256, 0, stream>>>(Fb, capb, Lout, realn, lsc, out);
}

// Round 4
// 403.775 us; speedup vs baseline: 1.4961x; 1.0160x over previous
//
#include <hip/hip_runtime.h>

#define P_PTS 131072
#define CDIM  512
#define MCAP  1024
#define TLEN  262144
#define PORIG 163840

typedef unsigned short u16;
typedef unsigned char  u8;
typedef __attribute__((ext_vector_type(8))) short short8;
typedef __attribute__((ext_vector_type(4))) float f32x4;
typedef __attribute__((ext_vector_type(8))) int int8v;
typedef __attribute__((ext_vector_type(4))) int int4v;

__device__ __forceinline__ u16 f2bf(float f) {
    unsigned u = __float_as_uint(f);
    unsigned r = (u + 0x7FFFu + ((u >> 16) & 1u)) >> 16;
    return (u16)r;
}
// OCP e4m3 decode: normals AND subnormals via f32-subnormal trick
__device__ __forceinline__ float d_e4m3(unsigned x) {
    float f = __uint_as_float((x & 0x7Fu) << 20) * 0x1p120f;
    return __uint_as_float(__float_as_uint(f) | ((x & 0x80u) << 24));
}
__device__ __forceinline__ void ld16(const void* g, void* l) {
    __builtin_amdgcn_global_load_lds(
        (const __attribute__((address_space(1))) void*)g,
        (__attribute__((address_space(3))) void*)l, 16, 0, 0);
}

// ---- fused: gather+normalize (blocks 0..32767), cap cast bf16 + ptom scatter
//      (32768..33279), lse_sum zero (33280..33791), B pre-swizzle (33792..33919)
__global__ __launch_bounds__(256) void gather_prep(
    const float* __restrict__ adapter, const int* __restrict__ v2p,
    const float* __restrict__ cap, const int* __restrict__ oidx,
    u8* __restrict__ feats8, u16* __restrict__ capb, u8* __restrict__ Bswz,
    int* __restrict__ ptom, float* __restrict__ lse_sum) {
    int b = blockIdx.x, tid = threadIdx.x;
    if (b < 32768) {
        int p = b * 4 + (tid >> 6);
        int lane = tid & 63;
        int vrow = v2p[p];
        const float4* src = (const float4*)(adapter + (size_t)vrow * CDIM);
        float4 x0 = src[lane * 2];
        float4 x1 = src[lane * 2 + 1];
        float ss = x0.x*x0.x + x0.y*x0.y + x0.z*x0.z + x0.w*x0.w
                 + x1.x*x1.x + x1.y*x1.y + x1.z*x1.z + x1.w*x1.w;
        #pragma unroll
        for (int off = 32; off >= 1; off >>= 1) ss += __shfl_xor(ss, off, 64);
        float inv = 1.0f / fmaxf(sqrtf(ss), 1e-12f);
        int lo = __builtin_amdgcn_cvt_pk_fp8_f32(x0.x*inv, x0.y*inv, 0, false);
        lo = __builtin_amdgcn_cvt_pk_fp8_f32(x0.z*inv, x0.w*inv, lo, true);
        int hi = __builtin_amdgcn_cvt_pk_fp8_f32(x1.x*inv, x1.y*inv, 0, false);
        hi = __builtin_amdgcn_cvt_pk_fp8_f32(x1.z*inv, x1.w*inv, hi, true);
        uint2 w; w.x = (unsigned)lo; w.y = (unsigned)hi;
        *(uint2*)(feats8 + (size_t)p * CDIM + lane * 8) = w;
    } else if (b < 33280) {
        int t = (b - 32768) * 256 + tid;       // [0, 131072)
        int i = t * 4;
        float4 v = *(const float4*)(cap + i);
        u16* o = capb + i;
        o[0] = f2bf(v.x); o[1] = f2bf(v.y); o[2] = f2bf(v.z); o[3] = f2bf(v.w);
        atomicMax(&ptom[oidx[t]], t);          // last-write-wins == max (t increasing)
    } else if (b < 33792) {
        int j = (b - 33280) * 256 + tid;       // [0, 131072)
        lse_sum[j] = 0.0f;
    } else {
        // B pre-swizzle into MFMA fragment order: granule g2 (16 B) ->
        // c=g2&1, lane=(g2>>1)&63, j=(g2>>7)&3, kk=(g2>>9)&3, wn=(g2>>11)&1, c0=g2>>12
        int g2 = (b - 33792) * 256 + tid;      // [0, 32768)
        int c    = g2 & 1;
        int lane = (g2 >> 1) & 63;
        int j    = (g2 >> 7) & 3;
        int kk   = (g2 >> 9) & 3;
        int wn   = (g2 >> 11) & 1;
        int c0   = g2 >> 12;
        int col  = c0 * 128 + wn * 64 + j * 16 + (lane & 15);
        int kb   = kk * 128 + (lane >> 4) * 32 + c * 16;
        const float* s = cap + (size_t)col * CDIM + kb;
        unsigned w4[4];
        #pragma unroll
        for (int u = 0; u < 4; ++u) {
            int p = __builtin_amdgcn_cvt_pk_fp8_f32(s[u*4+0], s[u*4+1], 0, false);
            p = __builtin_amdgcn_cvt_pk_fp8_f32(s[u*4+2], s[u*4+3], p, true);
            w4[u] = (unsigned)p;
        }
        *(uint4*)(Bswz + (size_t)g2 * 16) = *(uint4*)w4;
    }
}

// ---- heavy GEMM: MX-fp8 K=128 MFMA, 128x128 tiles; A via LDS (XOR swizzle),
//      B direct-from-global in pre-swizzled fragment order (no barrier dep);
//      tail blocks (>=8192) do make_rows. Epilogue exp-reduce -> atomicAdd ----
__global__ __launch_bounds__(256) void lse_gemm(
    const u8* __restrict__ feats8, const u8* __restrict__ Bswz,
    const float* __restrict__ lsc, float* __restrict__ lse_sum,
    const int* __restrict__ ctpm, const int* __restrict__ ptom,
    unsigned* __restrict__ rows) {
    if (blockIdx.x >= 8192) {                  // make_rows tail
        int t = (blockIdx.x - 8192) * 256 + threadIdx.x;
        int g = ptom[ctpm[t]];
        rows[t] = (g < 0) ? ((unsigned)(g + P_PTS) | 0x80000000u) : (unsigned)g;
        return;
    }
    __shared__ __align__(16) u8 As[16384];
    const int tid  = threadIdx.x;
    const int wave = tid >> 6;
    const int lane = tid & 63;
    const unsigned id = blockIdx.x;
    const int c0   = (int)((id >> 3) & 7u);
    const int col0 = c0 * 128;
    const int row0 = (int)((id & 7u) + 8u * (id >> 6)) * 128;
    const int wm = (wave >> 1) * 64;
    const int wn1 = (wave & 1);
    const float sf = __expf(lsc[0]);

    f32x4 acc[4][4] = {};

    const int srow = tid >> 3;                 // 0..31
    const int kc   = (tid & 7) ^ (srow & 7);
    const u8* gA = feats8 + (size_t)(row0 + srow) * CDIM + kc * 16;
    u8* lA = As + wave * 1024;

    const int m = lane & 15;
    const int q = lane >> 4;
    const u8* rA1 = As + (size_t)((wm + m) * 8 + ((2*q)   ^ (m & 7))) * 16;
    const u8* rA2 = As + (size_t)((wm + m) * 8 + ((2*q+1) ^ (m & 7))) * 16;
    // B fragment base: (((c0*2+wn)*4+kk)*4+j)*2048 + lane*32 + 16c
    const u8* bw = Bswz + (size_t)(c0 * 2 + wn1) * 16 * 2048 + lane * 32;

    #pragma unroll
    for (int k0 = 0; k0 < CDIM; k0 += 128) {
        const int kk = k0 >> 7;
        // B loads: no LDS, no barrier dependency -> compiler pipelines on vmcnt
        int8v bv[4];
        #pragma unroll
        for (int j = 0; j < 4; ++j) {
            int4v lo = *(const int4v*)(bw + (kk * 4 + j) * 2048);
            int4v hi = *(const int4v*)(bw + (kk * 4 + j) * 2048 + 16);
            bv[j][0]=lo[0]; bv[j][1]=lo[1]; bv[j][2]=lo[2]; bv[j][3]=lo[3];
            bv[j][4]=hi[0]; bv[j][5]=hi[1]; bv[j][6]=hi[2]; bv[j][7]=hi[3];
        }
        __syncthreads();
        #pragma unroll
        for (int c = 0; c < 4; ++c)
            ld16(gA + (size_t)c * 32 * CDIM + k0, lA + c * 4096);
        __syncthreads();
        int8v af[4];
        #pragma unroll
        for (int i = 0; i < 4; ++i) {
            int4v lo = *(const int4v*)(rA1 + i * 2048);
            int4v hi = *(const int4v*)(rA2 + i * 2048);
            af[i][0]=lo[0]; af[i][1]=lo[1]; af[i][2]=lo[2]; af[i][3]=lo[3];
            af[i][4]=hi[0]; af[i][5]=hi[1]; af[i][6]=hi[2]; af[i][7]=hi[3];
        }
        #pragma unroll
        for (int i = 0; i < 4; ++i)
            #pragma unroll
            for (int j = 0; j < 4; ++j)
                acc[i][j] = __builtin_amdgcn_mfma_scale_f32_16x16x128_f8f6f4(
                    af[i], bv[j], acc[i][j], 0, 0, 0, 127, 0, 127); // e8m0 127 = x1.0
    }

    #pragma unroll
    for (int i = 0; i < 4; ++i) {
        float s4[4] = {0.f, 0.f, 0.f, 0.f};
        #pragma unroll
        for (int j = 0; j < 4; ++j)
            #pragma unroll
            for (int r = 0; r < 4; ++r)
                s4[r] += __expf(acc[i][j][r] * sf - sf);
        #pragma unroll
        for (int off = 8; off >= 1; off >>= 1)
            #pragma unroll
            for (int r = 0; r < 4; ++r)
                s4[r] += __shfl_xor(s4[r], off, 64);
        if (m == 0) {
            int rbase = row0 + wm + i * 16 + q * 4;
            #pragma unroll
            for (int r = 0; r < 4; ++r)
                atomicAdd(&lse_sum[rbase + r], s4[r]);
        }
    }
}

__device__ __forceinline__ int lower_bound(const int* __restrict__ a, int n, int key) {
    int lo = 0, hi = n;
    while (lo < hi) { int mid = (lo + hi) >> 1; if (a[mid] < key) lo = mid + 1; else hi = mid; }
    return lo;
}

// ---- per-segment: Fb[s] = sum feats rows (bf16), L[s] = sum log lse_sum, counts ----
__global__ __launch_bounds__(1024) void seg_reduce(
    const u8* __restrict__ feats8, const float* __restrict__ lse_sum,
    const unsigned* __restrict__ rows, const int* __restrict__ seg,
    const float* __restrict__ lsc,
    u16* __restrict__ Fb, float* __restrict__ Lout, float* __restrict__ realn) {
    int s = blockIdx.x;
    int tid = threadIdx.x, wave = tid >> 6, lane = tid & 63;
    int start = lower_bound(seg, TLEN, s);
    int end   = lower_bound(seg, TLEN, s + 1);
    float a[8] = {0,0,0,0,0,0,0,0};
    float Lacc = 0.f; int inv = 0;
    int r = start + wave;
    for (; r + 16 < end; r += 32) {
        unsigned p0 = rows[r], p1 = rows[r + 16];
        int r0 = (int)(p0 & 0x7FFFFFFFu), r1 = (int)(p1 & 0x7FFFFFFFu);
        uint2 v0 = *(const uint2*)(feats8 + (size_t)r0 * CDIM + lane * 8);
        uint2 v1 = *(const uint2*)(feats8 + (size_t)r1 * CDIM + lane * 8);
        if (lane == 0) {
            inv += (int)(p0 >> 31) + (int)(p1 >> 31);
            Lacc += __logf(lse_sum[r0]) + __logf(lse_sum[r1]);
        }
        a[0] += d_e4m3(v0.x);       a[1] += d_e4m3(v0.x >> 8);
        a[2] += d_e4m3(v0.x >> 16); a[3] += d_e4m3(v0.x >> 24);
        a[4] += d_e4m3(v0.y);       a[5] += d_e4m3(v0.y >> 8);
        a[6] += d_e4m3(v0.y >> 16); a[7] += d_e4m3(v0.y >> 24);
        a[0] += d_e4m3(v1.x);       a[1] += d_e4m3(v1.x >> 8);
        a[2] += d_e4m3(v1.x >> 16); a[3] += d_e4m3(v1.x >> 24);
        a[4] += d_e4m3(v1.y);       a[5] += d_e4m3(v1.y >> 8);
        a[6] += d_e4m3(v1.y >> 16); a[7] += d_e4m3(v1.y >> 24);
    }
    if (r < end) {
        unsigned p0 = rows[r];
        int r0 = (int)(p0 & 0x7FFFFFFFu);
        uint2 v0 = *(const uint2*)(feats8 + (size_t)r0 * CDIM + lane * 8);
        if (lane == 0) { inv += (int)(p0 >> 31); Lacc += __logf(lse_sum[r0]); }
        a[0] += d_e4m3(v0.x);       a[1] += d_e4m3(v0.x >> 8);
        a[2] += d_e4m3(v0.x >> 16); a[3] += d_e4m3(v0.x >> 24);
        a[4] += d_e4m3(v0.y);       a[5] += d_e4m3(v0.y >> 8);
        a[6] += d_e4m3(v0.y >> 16); a[7] += d_e4m3(v0.y >> 24);
    }
    __shared__ float pF[16][512];
    __shared__ float pL[16];
    __shared__ int   pI[16];
    #pragma unroll
    for (int u = 0; u < 8; ++u) pF[wave][lane * 8 + u] = a[u];
    if (lane == 0) { pL[wave] = Lacc; pI[wave] = inv; }
    __syncthreads();
    if (tid < 512) {
        float f = 0.f;
        #pragma unroll
        for (int w = 0; w < 16; ++w) f += pF[w][tid];
        Fb[(size_t)s * CDIM + tid] = f2bf(f);
    }
    if (tid == 0) {
        float cnt = (float)(end - start);
        float Ls = 0.f; int ninv = 0;
        #pragma unroll
        for (int w = 0; w < 16; ++w) { Ls += pL[w]; ninv += pI[w]; }
        realn[s] = cnt - (float)ninv;
        Lout[s] = Ls + __expf(lsc[0]) * cnt;   // each lse = sf + log(sum)
    }
}

// ---- pooled[s,m] = (sf*Fb[s].capb[m] - L[s]) * (1/real or 0); 64x64 bf16 MFMA ----
__global__ __launch_bounds__(256) void pooled_gemm(
    const u16* __restrict__ Fb, const u16* __restrict__ capb,
    const float* __restrict__ Lout, const float* __restrict__ realn,
    const float* __restrict__ lsc, float* __restrict__ out) {
    __shared__ __align__(16) u16 As[64 * 32];
    __shared__ __align__(16) u16 Bs[64 * 32];
    const int tid  = threadIdx.x;
    const int wave = tid >> 6;
    const int lane = tid & 63;
    const int col0 = blockIdx.x * 64;   // captions
    const int row0 = blockIdx.y * 64;   // segments
    const int wm = (wave >> 1) * 32;
    const int wn = (wave & 1) * 32;
    const float sf = __expf(lsc[0]);
    f32x4 acc[2][2] = {};
    const int srow = tid >> 2;          // 0..63
    const int scol = (tid & 3) * 8;
    const u16* gA0 = Fb   + (size_t)(row0 + srow) * CDIM + scol;
    const u16* gB0 = capb + (size_t)(col0 + srow) * CDIM + scol;
    u16* lA0 = As + wave * 512;
    u16* lB0 = Bs + wave * 512;
    const int mrow = lane & 15;
    const int quad = lane >> 4;
    const u16* rA = As + (wm + mrow) * 32 + quad * 8;
    const u16* rB = Bs + (wn + mrow) * 32 + quad * 8;
    #pragma unroll 4
    for (int k0 = 0; k0 < CDIM; k0 += 32) {
        __syncthreads();
        ld16(gA0 + k0, lA0);
        ld16(gB0 + k0, lB0);
        __syncthreads();
        short8 af[2], bfr[2];
        #pragma unroll
        for (int i = 0; i < 2; ++i) af[i]  = *(const short8*)(rA + i * 512);
        #pragma unroll
        for (int j = 0; j < 2; ++j) bfr[j] = *(const short8*)(rB + j * 512);
        #pragma unroll
        for (int i = 0; i < 2; ++i)
            #pragma unroll
            for (int j = 0; j < 2; ++j)
                acc[i][j] = __builtin_amdgcn_mfma_f32_16x16x32_bf16(
                    af[i], bfr[j], acc[i][j], 0, 0, 0);
    }
    #pragma unroll
    for (int i = 0; i < 2; ++i) {
        #pragma unroll
        for (int r = 0; r < 4; ++r) {
            int s = row0 + wm + i * 16 + quad * 4 + r;
            float rn = realn[s];
            float dn = rn > 0.f ? 1.0f / rn : 0.0f;
            float L = Lout[s];
            #pragma unroll
            for (int j = 0; j < 2; ++j) {
                int mc = col0 + wn + j * 16 + mrow;
                out[(size_t)s * MCAP + mc] = (sf * acc[i][j][r] - L) * dn;
            }
        }
    }
    if (col0 == 0 && tid < 64) {
        int s = row0 + tid;
        float rv = realn[s];
        out[MCAP * MCAP + s] = rv;
        out[MCAP * MCAP + MCAP + s] = (rv > 0.f) ? 1.0f : 0.0f;
    }
}

extern "C" void kernel_launch(void* const* d_in, const int* in_sizes, int n_in,
                              void* d_out, int out_size, void* d_ws, size_t ws_size,
                              hipStream_t stream) {
    const float* adapter = (const float*)d_in[0];
    const float* cap     = (const float*)d_in[1];
    const float* lsc     = (const float*)d_in[2];
    const int*   v2p     = (const int*)d_in[3];
    const int*   oidx    = (const int*)d_in[4];
    const int*   ctpm    = (const int*)d_in[5];
    const int*   seg     = (const int*)d_in[6];
    float* out = (float*)d_out;

    char* ws = (char*)d_ws;
    u8*       feats8  = (u8*)(ws);                                // 67,108,864 B
    u16*      capb    = (u16*)(ws + 67108864);                    //  1,048,576 B
    u8*       Bswz    = (u8*)(ws + 68157440);                     //    524,288 B
    float*    lse_sum = (float*)(ws + 68681728);                  //    524,288 B
    int*      ptom    = (int*)(ws + 69206016);                    //    655,360 B
    unsigned* rows    = (unsigned*)(ws + 69861376);               //  1,048,576 B
    u16*      Fb      = (u16*)(ws + 70909952);                    //  1,048,576 B
    float*    Lout    = (float*)(ws + 71958528);                  //      4,096 B
    float*    realn   = (float*)(ws + 71962624);                  //      4,096 B

    hipMemsetAsync(ptom, 0xFF, (size_t)PORIG * 4, stream);        // -1

    gather_prep<<<33920, 256, 0, stream>>>(adapter, v2p, cap, oidx,
                                           feats8, capb, Bswz, ptom, lse_sum);
    lse_gemm<<<8192 + TLEN / 256, 256, 0, stream>>>(feats8, Bswz, lsc, lse_sum,
                                                    ctpm, ptom, rows);
    seg_reduce<<<MCAP, 1024, 0, stream>>>(feats8, lse_sum, rows, seg, lsc, Fb, Lout, realn);
    pooled_gemm<<<dim3(MCAP / 64, MCAP / 64), 256, 0, stream>>>(Fb, capb, Lout, realn, lsc, out);
}